// Round 17
// baseline (59.417 us; speedup 1.0000x reference)
//
#include <hip/hip_runtime.h>

#define D_MODEL 256
#define TX 512
#define TM 512

__device__ __forceinline__ float fexp2(float x) { return __builtin_amdgcn_exp2f(x); }
__device__ __forceinline__ float frcp(float x)  { return __builtin_amdgcn_rcpf(x); }

// acc += sum_{i=0..7} w[i]/(1+a[i]*e[i]) with ONE v_rcp_f32 (exact algebra).
// Octet = two quads (lo, hi) combined: (N1*D2 + N2*D1) / (D1*D2).
__device__ __forceinline__ float oct(float4 aL, float4 aH, float4 eL, float4 eH,
                                     float4 wL, float4 wH, float acc) {
    float p1 = fmaf(aL.x, eL.x, 1.f);
    float p2 = fmaf(aL.y, eL.y, 1.f);
    float p3 = fmaf(aL.z, eL.z, 1.f);
    float p4 = fmaf(aL.w, eL.w, 1.f);
    float p5 = fmaf(aH.x, eH.x, 1.f);
    float p6 = fmaf(aH.y, eH.y, 1.f);
    float p7 = fmaf(aH.z, eH.z, 1.f);
    float p8 = fmaf(aH.w, eH.w, 1.f);
    float p12 = p1 * p2, p34 = p3 * p4;
    float p56 = p5 * p6, p78 = p7 * p8;
    float q12 = fmaf(wL.x, p2, wL.y * p1);
    float q34 = fmaf(wL.z, p4, wL.w * p3);
    float q56 = fmaf(wH.x, p6, wH.y * p5);
    float q78 = fmaf(wH.z, p8, wH.w * p7);
    float N1 = fmaf(q12, p34, q34 * p12);
    float D1 = p12 * p34;
    float N2 = fmaf(q56, p78, q78 * p56);
    float D2 = p56 * p78;
    float N = fmaf(N1, D2, N2 * D1);
    float D = D1 * D2;
    return fmaf(N, frcp(D), acc);
}

// Two NT-GEMMs; 64x64 tiles, 512-thread blocks (8 waves), double-buffered LDS.
// Grid (128, 1, 2), block 512. (r16 config, kept.)
__global__ __launch_bounds__(512) void gemm_exp2(
    const float* __restrict__ x,   const float* __restrict__ mem,
    const float* __restrict__ w1,  const float* __restrict__ b1,
    const float* __restrict__ w2,
    float* __restrict__ E1, float* __restrict__ E2p)
{
    const float C_SCALE = 2.8853900817779268f; // 2*log2(e)
    const int bid = (int)blockIdx.x;
    const float* A; const float* W;
    int r0, n0;
    if (blockIdx.z == 0) { A = x;  W = w1; r0 = (bid & 31) * 64; n0 = (bid >> 5) * 64; }
    else                 { A = w2; W = mem; r0 = (bid >> 5) * 64; n0 = (bid & 31) * 64; }

    __shared__ float As[2][16][68];
    __shared__ float Ws[2][16][68];
    const int t = threadIdx.x;
    const int tx = t & 15, ty = t >> 4;
    const int half = t >> 8;
    const int st = t & 255;
    const int rl = st >> 2, g = st & 3;
    float acc[2][4] = {};
    const float* Sp = (half == 0 ? A + (size_t)(r0 + rl) * 256
                                 : W + (size_t)(n0 + rl) * 256) + g * 4;

    {   // prologue: stage k0 = 0 into buffer 0
        float4 v = *(const float4*)Sp;
        float (*dst)[16][68] = (half == 0) ? &As[0] : &Ws[0];
        (*dst)[g*4+0][rl] = v.x; (*dst)[g*4+1][rl] = v.y;
        (*dst)[g*4+2][rl] = v.z; (*dst)[g*4+3][rl] = v.w;
    }
    __syncthreads();

    for (int k0 = 0; k0 < 16; ++k0) {
        const int cur = k0 & 1;
        float4 nv;
        if (k0 < 15) nv = *(const float4*)(Sp + (k0 + 1) * 16);
        #pragma unroll
        for (int kk = 0; kk < 16; ++kk) {
            float2 av = *(const float2*)&As[cur][kk][ty*2];
            float4 wv = *(const float4*)&Ws[cur][kk][tx*4];
            acc[0][0] = fmaf(av.x, wv.x, acc[0][0]);
            acc[0][1] = fmaf(av.x, wv.y, acc[0][1]);
            acc[0][2] = fmaf(av.x, wv.z, acc[0][2]);
            acc[0][3] = fmaf(av.x, wv.w, acc[0][3]);
            acc[1][0] = fmaf(av.y, wv.x, acc[1][0]);
            acc[1][1] = fmaf(av.y, wv.y, acc[1][1]);
            acc[1][2] = fmaf(av.y, wv.z, acc[1][2]);
            acc[1][3] = fmaf(av.y, wv.w, acc[1][3]);
        }
        if (k0 < 15) {
            const int nxt = cur ^ 1;
            float (*dst)[16][68] = (half == 0) ? &As[nxt] : &Ws[nxt];
            (*dst)[g*4+0][rl] = nv.x; (*dst)[g*4+1][rl] = nv.y;
            (*dst)[g*4+2][rl] = nv.z; (*dst)[g*4+3][rl] = nv.w;
            __syncthreads();
        }
    }

    if (blockIdx.z == 0) {
        #pragma unroll
        for (int i = 0; i < 2; ++i) {
            const int r = r0 + ty*2 + i;
            #pragma unroll
            for (int j = 0; j < 4; ++j) {
                const int n = n0 + tx*4 + j;
                E1[(size_t)r*256 + n] = fexp2(C_SCALE * (acc[i][j] + b1[n]));
            }
        }
    } else {
        #pragma unroll
        for (int i = 0; i < 2; ++i) {
            const int r = r0 + ty*2 + i;   // d index
            #pragma unroll
            for (int j = 0; j < 4; ++j) {
                const int n = n0 + tx*4 + j;  // gm index
                E2p[(size_t)(r >> 2)*8192 + (size_t)n*4 + (r & 3)] = fexp2(C_SCALE * acc[i][j]);
            }
        }
    }
}

// Fused: S = Wsum - 2*sum_d w[d]/(1+E1*E2), mask, 8-wave softmax, single-pass PV.
// Grid 512, block 512 (8 waves). Block owns 4 x-rows.
// Thread t: tm = t&255 -> m in {tm, tm+256}; dh = t>>8 -> d-half (128 d).
// Main loop: 16 iterations x 8 d (octet, one rcp per 8 evals).
__global__ __launch_bounds__(512) void fused_tanh_attn(
    const float* __restrict__ E1,     // [B*TX, D]
    const float* __restrict__ E2p,    // packed [(d>>2)][gm][4]
    const float* __restrict__ memory, // [B, TM, D]
    const int*   __restrict__ mask,   // [B, TM]
    const float* __restrict__ wst,    // [D]
    float* __restrict__ out,          // [B*TX, D]
    float* __restrict__ Sout)         // [B*TX, TM]
{
    const float LOG2E = 1.4426950408889634f;
    const int t = threadIdx.x;
    // XCD-aware bijective swizzle (512 = 8*64)
    const int blk = (int)((blockIdx.x & 7) * 64 + (blockIdx.x >> 3));
    const int b = blk >> 7;                // 128 blocks per batch
    const int x0 = (blk & 127) * 4;
    const int wave = t >> 6, lane = t & 63;
    const int tm = t & 255;
    const int dh = t >> 8;                 // 0 or 1

    __shared__ float i1R[4][D_MODEL];       // 4 KB
    __shared__ float wsh[D_MODEL];          // 1 KB
    __shared__ float P[4][TM];              // 8 KB
    __shared__ float mneg[TM];              // 2 KB
    __shared__ float opart[8][4][D_MODEL];  // 32 KB
    __shared__ float wpart[8];
    __shared__ float smax[4][2], ssum[4][2];

    // stage E1 rows, wst, mask
    {
        const float* i1g = E1 + ((size_t)b * TX + x0) * D_MODEL;
        const int row = t >> 7, col2 = (t & 127) * 2;
        float2 v = *(const float2*)(i1g + (size_t)row * D_MODEL + col2);
        *(float2*)&i1R[row][col2] = v;
    }
    if (t < 256) wsh[t] = wst[t];
    mneg[t] = mask[b*TM + t] ? 0.f : -__builtin_inff();

    // Wsum = sum(wst)
    {
        float s = (t < 256) ? wst[t] : 0.f;
        #pragma unroll
        for (int off = 32; off > 0; off >>= 1) s += __shfl_xor(s, off);
        if (lane == 0) wpart[wave] = s;
    }

    // first E2 octet loads (both m streams, this thread's d-half)
    const int g0 = dh * 32;
    const float* e2ptrA = E2p + ((size_t)b * TM + tm) * 4;
    const float* e2ptrB = e2ptrA + 1024;   // m + 256
    float4 eaL = *(const float4*)(e2ptrA + (size_t)g0 * 8192);
    float4 eaH = *(const float4*)(e2ptrA + (size_t)(g0 + 1) * 8192);
    float4 ebL = *(const float4*)(e2ptrB + (size_t)g0 * 8192);
    float4 ebH = *(const float4*)(e2ptrB + (size_t)(g0 + 1) * 8192);

    __syncthreads();
    const float Wsum = wpart[0] + wpart[1] + wpart[2] + wpart[3]
                     + wpart[4] + wpart[5] + wpart[6] + wpart[7];

    // main loop: 16 iterations of 8 d; 1-pair-deep prefetch; one rcp per octet
    float accA[4] = {}, accB[4] = {};
    for (int gi = 0; gi < 16; ++gi) {
        const int g = g0 + 2 * gi;
        float4 eaLn = eaL, eaHn = eaH, ebLn = ebL, ebHn = ebH;
        if (gi < 15) {
            eaLn = *(const float4*)(e2ptrA + (size_t)(g + 2) * 8192);
            eaHn = *(const float4*)(e2ptrA + (size_t)(g + 3) * 8192);
            ebLn = *(const float4*)(e2ptrB + (size_t)(g + 2) * 8192);
            ebHn = *(const float4*)(e2ptrB + (size_t)(g + 3) * 8192);
        }
        float4 wL = *(const float4*)&wsh[g * 4];
        float4 wH = *(const float4*)&wsh[g * 4 + 4];
        #pragma unroll
        for (int r = 0; r < 4; ++r) {
            float4 aL = *(const float4*)&i1R[r][g * 4];
            float4 aH = *(const float4*)&i1R[r][g * 4 + 4];
            accA[r] = oct(aL, aH, eaL, eaH, wL, wH, accA[r]);
            accB[r] = oct(aL, aH, ebL, ebH, wL, wH, accB[r]);
        }
        eaL = eaLn; eaH = eaHn; ebL = ebLn; ebH = ebHn;
    }

    // combine d-halves through P, apply Wsum/mask
    if (dh == 0) {
        #pragma unroll
        for (int r = 0; r < 4; ++r) {
            P[r][tm]       = accA[r];
            P[r][tm + 256] = accB[r];
        }
    }
    __syncthreads();
    if (dh == 1) {
        const float mnA = mneg[tm], mnB = mneg[tm + 256];
        #pragma unroll
        for (int r = 0; r < 4; ++r) {
            P[r][tm]       = Wsum - 2.f * (P[r][tm]       + accA[r]) + mnA;
            P[r][tm + 256] = Wsum - 2.f * (P[r][tm + 256] + accB[r]) + mnB;
        }
    }
    __syncthreads();

    // 8-wave softmax: wave -> (row r = wave&3, half h = wave>>2), 4 values/lane
    {
        const int r = wave & 3, h = wave >> 2;
        const int base = h * 256 + lane * 4;
        float4 v4 = *(const float4*)&P[r][base];
        float v0 = v4.x, v1 = v4.y, v2 = v4.z, v3 = v4.w;
        float mx = fmaxf(fmaxf(v0, v1), fmaxf(v2, v3));
        #pragma unroll
        for (int off = 32; off > 0; off >>= 1) mx = fmaxf(mx, __shfl_xor(mx, off));
        float e0 = fexp2((v0 - mx) * LOG2E);
        float e1 = fexp2((v1 - mx) * LOG2E);
        float e2 = fexp2((v2 - mx) * LOG2E);
        float e3 = fexp2((v3 - mx) * LOG2E);
        float sum = (e0 + e1) + (e2 + e3);
        #pragma unroll
        for (int off = 32; off > 0; off >>= 1) sum += __shfl_xor(sum, off);
        if (lane == 0) { smax[r][h] = mx; ssum[r][h] = sum; }
        __syncthreads();
        const float m0 = smax[r][0], m1 = smax[r][1];
        const float mg = fmaxf(m0, m1);
        const float tot = ssum[r][0] * fexp2((m0 - mg) * LOG2E)
                        + ssum[r][1] * fexp2((m1 - mg) * LOG2E);
        const float fac = fexp2((mx - mg) * LOG2E) * frcp(tot);
        float4 p = {e0 * fac, e1 * fac, e2 * fac, e3 * fac};
        *(float4*)&P[r][base] = p;
        *(float4*)(Sout + ((size_t)b*TX + x0 + r) * TM + base) = p;
    }
    __syncthreads();

    // PV: wave owns m in [wave*64, wave*64+64); all 4 rows per load.
    {
        const int m0 = wave * 64;
        const float* memp = memory + ((size_t)b * TM + m0) * D_MODEL + lane * 4;
        float4 o0 = {0,0,0,0}, o1 = {0,0,0,0}, o2 = {0,0,0,0}, o3 = {0,0,0,0};
        for (int c = 0; c < 16; ++c) {
            float4 p0 = *(const float4*)&P[0][m0 + c*4];
            float4 p1 = *(const float4*)&P[1][m0 + c*4];
            float4 p2 = *(const float4*)&P[2][m0 + c*4];
            float4 p3 = *(const float4*)&P[3][m0 + c*4];
            #pragma unroll
            for (int j = 0; j < 4; ++j) {
                float4 mv = *(const float4*)(memp + (size_t)(c*4 + j) * D_MODEL);
                const float q0 = (j==0)?p0.x:(j==1)?p0.y:(j==2)?p0.z:p0.w;
                const float q1 = (j==0)?p1.x:(j==1)?p1.y:(j==2)?p1.z:p1.w;
                const float q2 = (j==0)?p2.x:(j==1)?p2.y:(j==2)?p2.z:p2.w;
                const float q3 = (j==0)?p3.x:(j==1)?p3.y:(j==2)?p3.z:p3.w;
                o0.x = fmaf(q0, mv.x, o0.x); o0.y = fmaf(q0, mv.y, o0.y);
                o0.z = fmaf(q0, mv.z, o0.z); o0.w = fmaf(q0, mv.w, o0.w);
                o1.x = fmaf(q1, mv.x, o1.x); o1.y = fmaf(q1, mv.y, o1.y);
                o1.z = fmaf(q1, mv.z, o1.z); o1.w = fmaf(q1, mv.w, o1.w);
                o2.x = fmaf(q2, mv.x, o2.x); o2.y = fmaf(q2, mv.y, o2.y);
                o2.z = fmaf(q2, mv.z, o2.z); o2.w = fmaf(q2, mv.w, o2.w);
                o3.x = fmaf(q3, mv.x, o3.x); o3.y = fmaf(q3, mv.y, o3.y);
                o3.z = fmaf(q3, mv.z, o3.z); o3.w = fmaf(q3, mv.w, o3.w);
            }
        }
        *(float4*)&opart[wave][0][lane*4] = o0;
        *(float4*)&opart[wave][1][lane*4] = o1;
        *(float4*)&opart[wave][2][lane*4] = o2;
        *(float4*)&opart[wave][3][lane*4] = o3;
    }
    __syncthreads();

    // combine 8 wave-partials: 1024 outputs, 2 per thread
    {
        #pragma unroll
        for (int k = 0; k < 2; ++k) {
            const int idx = t + k * 512;
            const int row = idx >> 8, d0 = idx & 255;
            float s = 0.f;
            #pragma unroll
            for (int w = 0; w < 8; ++w) s += opart[w][row][d0];
            out[((size_t)b*TX + x0 + row) * D_MODEL + d0] = s;
        }
    }
}

extern "C" void kernel_launch(void* const* d_in, const int* in_sizes, int n_in,
                              void* d_out, int out_size, void* d_ws, size_t ws_size,
                              hipStream_t stream) {
    const float* x    = (const float*)d_in[0];
    const float* mem  = (const float*)d_in[1];
    const int*   mask = (const int*)d_in[2];
    const float* w1   = (const float*)d_in[3];
    const float* b1   = (const float*)d_in[4];
    const float* w2   = (const float*)d_in[5];
    const float* wst  = (const float*)d_in[6];

    float* out  = (float*)d_out;                  // [4*512*256]
    float* Sout = out + 4 * 512 * 256;            // [4*512*512]
    float* E1   = (float*)d_ws;                   // 524288 floats (2 MB), [2048][256]
    float* E2p  = E1 + 4 * 512 * 256;             // 524288 floats (2 MB), packed

    dim3 gg(128, 1, 2);
    gemm_exp2<<<gg, 512, 0, stream>>>(x, mem, w1, b1, w2, E1, E2p);
    fused_tanh_attn<<<512, 512, 0, stream>>>(E1, E2p, mem, mask, wst, out, Sout);
}

// Round 18
// 56.806 us; speedup vs baseline: 1.0460x; 1.0460x over previous
//
#include <hip/hip_runtime.h>

#define D_MODEL 256
#define TX 512
#define TM 512

__device__ __forceinline__ float fexp2(float x) { return __builtin_amdgcn_exp2f(x); }
__device__ __forceinline__ float frcp(float x)  { return __builtin_amdgcn_rcpf(x); }

// acc += sum_{i=0..3} w[i]/(1+a[i]*e[i])  with ONE v_rcp_f32 (exact algebra).
__device__ __forceinline__ float quad(float4 a, float4 e, float4 w, float acc) {
    float p1 = fmaf(a.x, e.x, 1.f);
    float p2 = fmaf(a.y, e.y, 1.f);
    float p3 = fmaf(a.z, e.z, 1.f);
    float p4 = fmaf(a.w, e.w, 1.f);
    float p12 = p1 * p2;
    float p34 = p3 * p4;
    float q12 = fmaf(w.x, p2, w.y * p1);
    float q34 = fmaf(w.z, p4, w.w * p3);
    float N   = fmaf(q12, p34, q34 * p12);
    float D   = p12 * p34;
    return fmaf(N, frcp(D), acc);
}

// Two NT-GEMMs; 64x64 tiles, 512-thread blocks (8 waves), double-buffered LDS.
// Grid (128, 1, 2), block 512.
__global__ __launch_bounds__(512) void gemm_exp2(
    const float* __restrict__ x,   const float* __restrict__ mem,
    const float* __restrict__ w1,  const float* __restrict__ b1,
    const float* __restrict__ w2,
    float* __restrict__ E1, float* __restrict__ E2p)
{
    const float C_SCALE = 2.8853900817779268f; // 2*log2(e)
    const int bid = (int)blockIdx.x;
    const float* A; const float* W;
    int r0, n0;
    if (blockIdx.z == 0) { A = x;  W = w1; r0 = (bid & 31) * 64; n0 = (bid >> 5) * 64; }
    else                 { A = w2; W = mem; r0 = (bid >> 5) * 64; n0 = (bid & 31) * 64; }

    __shared__ float As[2][16][68];
    __shared__ float Ws[2][16][68];
    const int t = threadIdx.x;
    const int tx = t & 15, ty = t >> 4;         // outputs: rows r0+ty*2+{0,1}, cols n0+tx*4+{0..3}
    const int half = t >> 8;                    // 0: stage A, 1: stage W
    const int st = t & 255;
    const int rl = st >> 2, g = st & 3;         // 64 rows x 4 k-groups
    float acc[2][4] = {};
    const float* Sp = (half == 0 ? A + (size_t)(r0 + rl) * 256
                                 : W + (size_t)(n0 + rl) * 256) + g * 4;

    {   // prologue: stage k0 = 0 into buffer 0
        float4 v = *(const float4*)Sp;
        float (*dst)[16][68] = (half == 0) ? &As[0] : &Ws[0];
        (*dst)[g*4+0][rl] = v.x; (*dst)[g*4+1][rl] = v.y;
        (*dst)[g*4+2][rl] = v.z; (*dst)[g*4+3][rl] = v.w;
    }
    __syncthreads();

    for (int k0 = 0; k0 < 16; ++k0) {
        const int cur = k0 & 1;
        float4 nv;
        if (k0 < 15) nv = *(const float4*)(Sp + (k0 + 1) * 16);
        #pragma unroll
        for (int kk = 0; kk < 16; ++kk) {
            float2 av = *(const float2*)&As[cur][kk][ty*2];
            float4 wv = *(const float4*)&Ws[cur][kk][tx*4];
            acc[0][0] = fmaf(av.x, wv.x, acc[0][0]);
            acc[0][1] = fmaf(av.x, wv.y, acc[0][1]);
            acc[0][2] = fmaf(av.x, wv.z, acc[0][2]);
            acc[0][3] = fmaf(av.x, wv.w, acc[0][3]);
            acc[1][0] = fmaf(av.y, wv.x, acc[1][0]);
            acc[1][1] = fmaf(av.y, wv.y, acc[1][1]);
            acc[1][2] = fmaf(av.y, wv.z, acc[1][2]);
            acc[1][3] = fmaf(av.y, wv.w, acc[1][3]);
        }
        if (k0 < 15) {
            const int nxt = cur ^ 1;
            float (*dst)[16][68] = (half == 0) ? &As[nxt] : &Ws[nxt];
            (*dst)[g*4+0][rl] = nv.x; (*dst)[g*4+1][rl] = nv.y;
            (*dst)[g*4+2][rl] = nv.z; (*dst)[g*4+3][rl] = nv.w;
            __syncthreads();
        }
    }

    if (blockIdx.z == 0) {
        #pragma unroll
        for (int i = 0; i < 2; ++i) {
            const int r = r0 + ty*2 + i;
            #pragma unroll
            for (int j = 0; j < 4; ++j) {
                const int n = n0 + tx*4 + j;
                E1[(size_t)r*256 + n] = fexp2(C_SCALE * (acc[i][j] + b1[n]));
            }
        }
    } else {
        #pragma unroll
        for (int i = 0; i < 2; ++i) {
            const int r = r0 + ty*2 + i;   // d index
            #pragma unroll
            for (int j = 0; j < 4; ++j) {
                const int n = n0 + tx*4 + j;  // gm index
                E2p[(size_t)(r >> 2)*8192 + (size_t)n*4 + (r & 3)] = fexp2(C_SCALE * acc[i][j]);
            }
        }
    }
}

// Fused: S = Wsum - 2*sum_d w[d]/(1+E1*E2), mask, 8-wave softmax, single-pass PV.
// Grid 512 (= B*TX/4), block 512 (8 waves). Block owns 4 x-rows.
// Thread t: tm = t&255 -> m in {tm, tm+256}; dh = t>>8 -> d-half (128 d).
__global__ __launch_bounds__(512) void fused_tanh_attn(
    const float* __restrict__ E1,     // [B*TX, D]
    const float* __restrict__ E2p,    // packed [(d>>2)][gm][4]
    const float* __restrict__ memory, // [B, TM, D]
    const int*   __restrict__ mask,   // [B, TM]
    const float* __restrict__ wst,    // [D]
    float* __restrict__ out,          // [B*TX, D]
    float* __restrict__ Sout)         // [B*TX, TM]
{
    const float LOG2E = 1.4426950408889634f;
    const int t = threadIdx.x;
    // XCD-aware bijective swizzle (512 = 8*64)
    const int blk = (int)((blockIdx.x & 7) * 64 + (blockIdx.x >> 3));
    const int b = blk >> 7;                // 128 blocks per batch
    const int x0 = (blk & 127) * 4;
    const int wave = t >> 6, lane = t & 63;
    const int tm = t & 255;
    const int dh = t >> 8;                 // 0 or 1

    __shared__ float i1R[4][D_MODEL];       // 4 KB
    __shared__ float wsh[D_MODEL];          // 1 KB
    __shared__ float P[4][TM];              // 8 KB
    __shared__ float mneg[TM];              // 2 KB
    __shared__ float opart[8][4][D_MODEL];  // 32 KB
    __shared__ float wpart[8];
    __shared__ float smax[4][2], ssum[4][2];

    // stage E1 rows, wst, mask
    {
        const float* i1g = E1 + ((size_t)b * TX + x0) * D_MODEL;
        const int row = t >> 7, col2 = (t & 127) * 2;
        float2 v = *(const float2*)(i1g + (size_t)row * D_MODEL + col2);
        *(float2*)&i1R[row][col2] = v;
    }
    if (t < 256) wsh[t] = wst[t];
    mneg[t] = mask[b*TM + t] ? 0.f : -__builtin_inff();

    // Wsum = sum(wst)
    {
        float s = (t < 256) ? wst[t] : 0.f;
        #pragma unroll
        for (int off = 32; off > 0; off >>= 1) s += __shfl_xor(s, off);
        if (lane == 0) wpart[wave] = s;
    }

    // first E2 group loads (both m streams, this thread's d-half)
    const int g0 = dh * 32;
    const float* e2ptrA = E2p + ((size_t)b * TM + tm) * 4;
    const float* e2ptrB = e2ptrA + 1024;   // m + 256
    float4 e2a = *(const float4*)(e2ptrA + (size_t)g0 * 8192);
    float4 e2b = *(const float4*)(e2ptrB + (size_t)g0 * 8192);

    __syncthreads();
    const float Wsum = wpart[0] + wpart[1] + wpart[2] + wpart[3]
                     + wpart[4] + wpart[5] + wpart[6] + wpart[7];

    // main loop: 32 groups of 4 d; 1-deep prefetch; one rcp per quad
    float accA[4] = {}, accB[4] = {};
    #pragma unroll 2
    for (int gi = 0; gi < 32; ++gi) {
        const int g = g0 + gi;
        float4 e2an = e2a, e2bn = e2b;
        if (gi < 31) {
            e2an = *(const float4*)(e2ptrA + (size_t)(g + 1) * 8192);
            e2bn = *(const float4*)(e2ptrB + (size_t)(g + 1) * 8192);
        }
        float4 w4 = *(const float4*)&wsh[g * 4];
        #pragma unroll
        for (int r = 0; r < 4; ++r) {
            float4 a = *(const float4*)&i1R[r][g * 4];
            accA[r] = quad(a, e2a, w4, accA[r]);
            accB[r] = quad(a, e2b, w4, accB[r]);
        }
        e2a = e2an; e2b = e2bn;
    }

    // combine d-halves through P, apply Wsum/mask
    if (dh == 0) {
        #pragma unroll
        for (int r = 0; r < 4; ++r) {
            P[r][tm]       = accA[r];
            P[r][tm + 256] = accB[r];
        }
    }
    __syncthreads();
    if (dh == 1) {
        const float mnA = mneg[tm], mnB = mneg[tm + 256];
        #pragma unroll
        for (int r = 0; r < 4; ++r) {
            P[r][tm]       = Wsum - 2.f * (P[r][tm]       + accA[r]) + mnA;
            P[r][tm + 256] = Wsum - 2.f * (P[r][tm + 256] + accB[r]) + mnB;
        }
    }
    __syncthreads();

    // 8-wave softmax: wave -> (row r = wave&3, half h = wave>>2), 4 values/lane
    {
        const int r = wave & 3, h = wave >> 2;
        const int base = h * 256 + lane * 4;
        float4 v4 = *(const float4*)&P[r][base];
        float v0 = v4.x, v1 = v4.y, v2 = v4.z, v3 = v4.w;
        float mx = fmaxf(fmaxf(v0, v1), fmaxf(v2, v3));
        #pragma unroll
        for (int off = 32; off > 0; off >>= 1) mx = fmaxf(mx, __shfl_xor(mx, off));
        float e0 = fexp2((v0 - mx) * LOG2E);
        float e1 = fexp2((v1 - mx) * LOG2E);
        float e2 = fexp2((v2 - mx) * LOG2E);
        float e3 = fexp2((v3 - mx) * LOG2E);
        float sum = (e0 + e1) + (e2 + e3);
        #pragma unroll
        for (int off = 32; off > 0; off >>= 1) sum += __shfl_xor(sum, off);
        if (lane == 0) { smax[r][h] = mx; ssum[r][h] = sum; }
        __syncthreads();
        const float m0 = smax[r][0], m1 = smax[r][1];
        const float mg = fmaxf(m0, m1);
        const float tot = ssum[r][0] * fexp2((m0 - mg) * LOG2E)
                        + ssum[r][1] * fexp2((m1 - mg) * LOG2E);
        const float fac = fexp2((mx - mg) * LOG2E) * frcp(tot);
        float4 p = {e0 * fac, e1 * fac, e2 * fac, e3 * fac};
        *(float4*)&P[r][base] = p;
        *(float4*)(Sout + ((size_t)b*TX + x0 + r) * TM + base) = p;
    }
    __syncthreads();

    // PV: wave owns m in [wave*64, wave*64+64); all 4 rows per load.
    // memory read exactly once per block; P read as broadcast float4.
    {
        const int m0 = wave * 64;
        const float* memp = memory + ((size_t)b * TM + m0) * D_MODEL + lane * 4;
        float4 o0 = {0,0,0,0}, o1 = {0,0,0,0}, o2 = {0,0,0,0}, o3 = {0,0,0,0};
        for (int c = 0; c < 16; ++c) {
            float4 p0 = *(const float4*)&P[0][m0 + c*4];
            float4 p1 = *(const float4*)&P[1][m0 + c*4];
            float4 p2 = *(const float4*)&P[2][m0 + c*4];
            float4 p3 = *(const float4*)&P[3][m0 + c*4];
            #pragma unroll
            for (int j = 0; j < 4; ++j) {
                float4 mv = *(const float4*)(memp + (size_t)(c*4 + j) * D_MODEL);
                const float q0 = (j==0)?p0.x:(j==1)?p0.y:(j==2)?p0.z:p0.w;
                const float q1 = (j==0)?p1.x:(j==1)?p1.y:(j==2)?p1.z:p1.w;
                const float q2 = (j==0)?p2.x:(j==1)?p2.y:(j==2)?p2.z:p2.w;
                const float q3 = (j==0)?p3.x:(j==1)?p3.y:(j==2)?p3.z:p3.w;
                o0.x = fmaf(q0, mv.x, o0.x); o0.y = fmaf(q0, mv.y, o0.y);
                o0.z = fmaf(q0, mv.z, o0.z); o0.w = fmaf(q0, mv.w, o0.w);
                o1.x = fmaf(q1, mv.x, o1.x); o1.y = fmaf(q1, mv.y, o1.y);
                o1.z = fmaf(q1, mv.z, o1.z); o1.w = fmaf(q1, mv.w, o1.w);
                o2.x = fmaf(q2, mv.x, o2.x); o2.y = fmaf(q2, mv.y, o2.y);
                o2.z = fmaf(q2, mv.z, o2.z); o2.w = fmaf(q2, mv.w, o2.w);
                o3.x = fmaf(q3, mv.x, o3.x); o3.y = fmaf(q3, mv.y, o3.y);
                o3.z = fmaf(q3, mv.z, o3.z); o3.w = fmaf(q3, mv.w, o3.w);
            }
        }
        *(float4*)&opart[wave][0][lane*4] = o0;
        *(float4*)&opart[wave][1][lane*4] = o1;
        *(float4*)&opart[wave][2][lane*4] = o2;
        *(float4*)&opart[wave][3][lane*4] = o3;
    }
    __syncthreads();

    // combine 8 wave-partials: 1024 outputs, 2 per thread
    {
        #pragma unroll
        for (int k = 0; k < 2; ++k) {
            const int idx = t + k * 512;
            const int row = idx >> 8, d0 = idx & 255;
            float s = 0.f;
            #pragma unroll
            for (int w = 0; w < 8; ++w) s += opart[w][row][d0];
            out[((size_t)b*TX + x0 + row) * D_MODEL + d0] = s;
        }
    }
}

extern "C" void kernel_launch(void* const* d_in, const int* in_sizes, int n_in,
                              void* d_out, int out_size, void* d_ws, size_t ws_size,
                              hipStream_t stream) {
    const float* x    = (const float*)d_in[0];
    const float* mem  = (const float*)d_in[1];
    const int*   mask = (const int*)d_in[2];
    const float* w1   = (const float*)d_in[3];
    const float* b1   = (const float*)d_in[4];
    const float* w2   = (const float*)d_in[5];
    const float* wst  = (const float*)d_in[6];

    float* out  = (float*)d_out;                  // [4*512*256]
    float* Sout = out + 4 * 512 * 256;            // [4*512*512]
    float* E1   = (float*)d_ws;                   // 524288 floats (2 MB), [2048][256]
    float* E2p  = E1 + 4 * 512 * 256;             // 524288 floats (2 MB), packed

    dim3 gg(128, 1, 2);
    gemm_exp2<<<gg, 512, 0, stream>>>(x, mem, w1, b1, w2, E1, E2p);
    fused_tanh_attn<<<512, 512, 0, stream>>>(E1, E2p, mem, mask, wst, out, Sout);
}